// Round 1
// baseline (789.885 us; speedup 1.0000x reference)
//
#include <hip/hip_runtime.h>

// ComposeTransform: out = compose([t1,t2,t3]) with dense displacement fields.
//   r   = t3 + interp(t2, grid + t3)
//   out = r  + interp(t1, grid + r)
// Trilinear interp with clip-to-border (nearest extrapolation), matching
// neurite interpn: loc clipped to [0, dim-1]; floor/ceil corners; weight of
// floor corner = (loc1 - loc) with loc1 = min(loc0+1, dim-1).

#define BB 2
#define DD 128
#define HH 160
#define WW 192

__global__ __launch_bounds__(256) void warp_add_kernel(
    const float* __restrict__ vol,    // field being sampled   [B,D,H,W,3]
    const float* __restrict__ shift,  // current transform     [B,D,H,W,3]
    float* __restrict__ out,          // shift + interp(vol, grid+shift)
    long nvox_per_batch, long nvox_total)
{
    long idx = (long)blockIdx.x * blockDim.x + threadIdx.x;
    if (idx >= nvox_total) return;

    long vb = idx % nvox_per_batch;
    int  b  = (int)(idx / nvox_per_batch);
    int  w  = (int)(vb % WW);
    long t  = vb / WW;
    int  h  = (int)(t % HH);
    int  d  = (int)(t / HH);

    const float* sp = shift + idx * 3;
    float sx = sp[0], sy = sp[1], sz = sp[2];

    // absolute sample coords, clipped to volume
    float lx = fminf(fmaxf((float)d + sx, 0.f), (float)(DD - 1));
    float ly = fminf(fmaxf((float)h + sy, 0.f), (float)(HH - 1));
    float lz = fminf(fmaxf((float)w + sz, 0.f), (float)(WW - 1));

    float fx = floorf(lx), fy = floorf(ly), fz = floorf(lz);
    int x0 = (int)fx, y0 = (int)fy, z0 = (int)fz;
    int x1 = min(x0 + 1, DD - 1);
    int y1 = min(y0 + 1, HH - 1);
    int z1 = min(z0 + 1, WW - 1);

    // weight of floor corner = loc1 - loc (matches reference exactly,
    // including the loc==max edge where x1==x0 -> weight 0)
    float wx0 = (float)x1 - lx;
    float wy0 = (float)y1 - ly;
    float wz0 = (float)z1 - lz;
    float wx1 = 1.f - wx0;
    float wy1 = 1.f - wy0;
    float wz1 = 1.f - wz0;

    const float* base = vol + (long)b * nvox_per_batch * 3;

    float ax = 0.f, ay = 0.f, az = 0.f;
#define CORNER(X, Y, Z, WT) do {                                            \
        const float* cp = base + ((((long)(X) * HH + (Y)) * WW + (Z)) * 3); \
        float wt_ = (WT);                                                   \
        ax = fmaf(wt_, cp[0], ax);                                          \
        ay = fmaf(wt_, cp[1], ay);                                          \
        az = fmaf(wt_, cp[2], az);                                          \
    } while (0)

    CORNER(x0, y0, z0, wx0 * wy0 * wz0);
    CORNER(x0, y0, z1, wx0 * wy0 * wz1);
    CORNER(x0, y1, z0, wx0 * wy1 * wz0);
    CORNER(x0, y1, z1, wx0 * wy1 * wz1);
    CORNER(x1, y0, z0, wx1 * wy0 * wz0);
    CORNER(x1, y0, z1, wx1 * wy0 * wz1);
    CORNER(x1, y1, z0, wx1 * wy1 * wz0);
    CORNER(x1, y1, z1, wx1 * wy1 * wz1);
#undef CORNER

    float* op = out + idx * 3;
    op[0] = sx + ax;
    op[1] = sy + ay;
    op[2] = sz + az;
}

extern "C" void kernel_launch(void* const* d_in, const int* in_sizes, int n_in,
                              void* d_out, int out_size, void* d_ws, size_t ws_size,
                              hipStream_t stream) {
    const float* t1 = (const float*)d_in[0];
    const float* t2 = (const float*)d_in[1];
    const float* t3 = (const float*)d_in[2];
    float* out = (float*)d_out;
    float* r   = (float*)d_ws;   // intermediate composed field, 94.4 MB

    const long nvb = (long)DD * HH * WW;        // voxels per batch
    const long nvt = nvb * BB;                  // total voxels
    const int  block = 256;
    const long grid  = (nvt + block - 1) / block;

    // Pass A: r = t3 + interp(t2, grid + t3)
    warp_add_kernel<<<grid, block, 0, stream>>>(t2, t3, r, nvb, nvt);
    // Pass B: out = r + interp(t1, grid + r)
    warp_add_kernel<<<grid, block, 0, stream>>>(t1, r, out, nvb, nvt);
}

// Round 2
// 750.905 us; speedup vs baseline: 1.0519x; 1.0519x over previous
//
#include <hip/hip_runtime.h>

// ComposeTransform: out = compose([t1,t2,t3]) with dense displacement fields.
//   r   = t3 + interp(t2, grid + t3)
//   out = r  + interp(t1, grid + r)
// R1 -> R2: 3D-tiled blocks (2D x 2H x 64W) + XCD-aware block swizzle so the
// gather halo (x±1, y±1 rows) is reused within one XCD's 4 MiB L2.
// R1 counters showed FETCH=550 MB vs ~190 MB ideal (4.8x vol over-fetch,
// cross-XCD duplication of shared corner cachelines).

#define BB 2
#define DD 128
#define HH 160
#define WW 192

#define WT_TILES 3   // 192/64
#define HT_TILES 80  // 160/2
#define DT_TILES 64  // 128/2
#define NBLOCKS (WT_TILES * HT_TILES * DT_TILES * BB)  // 30720
#define PER_XCD (NBLOCKS / 8)                          // 3840

__global__ __launch_bounds__(256) void warp_add_kernel(
    const float* __restrict__ vol,    // field being sampled   [B,D,H,W,3]
    const float* __restrict__ shift,  // current transform     [B,D,H,W,3]
    float* __restrict__ out)          // shift + interp(vol, grid+shift)
{
    // XCD swizzle: blocks dispatched round-robin over 8 XCDs; give each XCD a
    // contiguous spatial slab so halo cachelines are reused within its L2.
    unsigned bid  = blockIdx.x;
    unsigned sbid = (bid & 7u) * PER_XCD + (bid >> 3);

    // decode tile: w fastest, then h, then d, then batch
    unsigned wt  = sbid % WT_TILES;  unsigned t0 = sbid / WT_TILES;
    unsigned ht  = t0 % HT_TILES;    unsigned t1 = t0 / HT_TILES;
    unsigned dt  = t1 % DT_TILES;    unsigned b  = t1 / DT_TILES;

    unsigned tid = threadIdx.x;
    int w = wt * 64 + (tid & 63);
    int h = ht * 2  + ((tid >> 6) & 1);
    int d = dt * 2  + (tid >> 7);

    const long nvb = (long)DD * HH * WW;
    long idx = (long)b * nvb + (((long)d * HH + h) * WW + w);

    const float* sp = shift + idx * 3;
    float sx = sp[0], sy = sp[1], sz = sp[2];

    // absolute sample coords, clipped to volume
    float lx = fminf(fmaxf((float)d + sx, 0.f), (float)(DD - 1));
    float ly = fminf(fmaxf((float)h + sy, 0.f), (float)(HH - 1));
    float lz = fminf(fmaxf((float)w + sz, 0.f), (float)(WW - 1));

    float fx = floorf(lx), fy = floorf(ly), fz = floorf(lz);
    int x0 = (int)fx, y0 = (int)fy, z0 = (int)fz;
    int x1 = min(x0 + 1, DD - 1);
    int y1 = min(y0 + 1, HH - 1);
    int z1 = min(z0 + 1, WW - 1);

    // weight of floor corner = loc1 - loc (matches reference exactly)
    float wx0 = (float)x1 - lx;
    float wy0 = (float)y1 - ly;
    float wz0 = (float)z1 - lz;
    float wx1 = 1.f - wx0;
    float wy1 = 1.f - wy0;
    float wz1 = 1.f - wz0;

    const float* base = vol + (long)b * nvb * 3;

    float ax = 0.f, ay = 0.f, az = 0.f;
#define CORNER(X, Y, Z, WT) do {                                            \
        const float* cp = base + ((((long)(X) * HH + (Y)) * WW + (Z)) * 3); \
        float wt_ = (WT);                                                   \
        ax = fmaf(wt_, cp[0], ax);                                          \
        ay = fmaf(wt_, cp[1], ay);                                          \
        az = fmaf(wt_, cp[2], az);                                          \
    } while (0)

    CORNER(x0, y0, z0, wx0 * wy0 * wz0);
    CORNER(x0, y0, z1, wx0 * wy0 * wz1);
    CORNER(x0, y1, z0, wx0 * wy1 * wz0);
    CORNER(x0, y1, z1, wx0 * wy1 * wz1);
    CORNER(x1, y0, z0, wx1 * wy0 * wz0);
    CORNER(x1, y0, z1, wx1 * wy0 * wz1);
    CORNER(x1, y1, z0, wx1 * wy1 * wz0);
    CORNER(x1, y1, z1, wx1 * wy1 * wz1);
#undef CORNER

    float* op = out + idx * 3;
    op[0] = sx + ax;
    op[1] = sy + ay;
    op[2] = sz + az;
}

extern "C" void kernel_launch(void* const* d_in, const int* in_sizes, int n_in,
                              void* d_out, int out_size, void* d_ws, size_t ws_size,
                              hipStream_t stream) {
    const float* t1 = (const float*)d_in[0];
    const float* t2 = (const float*)d_in[1];
    const float* t3 = (const float*)d_in[2];
    float* out = (float*)d_out;
    float* r   = (float*)d_ws;   // intermediate composed field, 94.4 MB

    // Pass A: r = t3 + interp(t2, grid + t3)
    warp_add_kernel<<<NBLOCKS, 256, 0, stream>>>(t2, t3, r);
    // Pass B: out = r + interp(t1, grid + r)
    warp_add_kernel<<<NBLOCKS, 256, 0, stream>>>(t1, r, out);
}

// Round 3
// 598.786 us; speedup vs baseline: 1.3191x; 1.2540x over previous
//
#include <hip/hip_runtime.h>
#include <hip/hip_fp16.h>

// ComposeTransform: out = compose([t1,t2,t3]) with dense displacement fields.
//   r   = t3 + interp(t2, grid + t3)
//   out = r  + interp(t1, grid + r)
// R2 -> R3: gathered volume staged as f16 padded to 8 B/voxel in d_ws.
//  - (z0,z1) corner pair of a row = 16 contiguous bytes -> 1 wide load
//    (4 scattered loads/voxel instead of 8)
//  - gather working set 94 -> 63 MB (L1/L2 hit rate up)
//  - intermediate r lives in d_out (pass B touches r only at own index)
// R2 counters: dur 296us/dispatch flat vs FETCH -30% => scatter-transaction /
// latency bound, not HBM-BW bound.

#define BB 2
#define DD 128
#define HH 160
#define WW 192

#define WT_TILES 3   // 192/64
#define HT_TILES 80  // 160/2
#define DT_TILES 64  // 128/2
#define NBLOCKS (WT_TILES * HT_TILES * DT_TILES * BB)  // 30720
#define PER_XCD (NBLOCKS / 8)                          // 3840

static __device__ __forceinline__ float3 cvt_h4(uint2 q) {
    // q = one padded voxel: halves (x,y) in q.x, (z,pad) in q.y
    float2 fa = __half22float2(*(const __half2*)&q.x);
    float  fz = __half2float(*(const __half*)&q.y);
    return make_float3(fa.x, fa.y, fz);
}

// Convert f32 [.,3] field to f16 padded [.,4] (8 B/voxel). 4 voxels/thread.
__global__ __launch_bounds__(256) void conv_f16_kernel(
    const float* __restrict__ src, uint2* __restrict__ dst)
{
    long i = (long)blockIdx.x * blockDim.x + threadIdx.x;  // 4-voxel group
    const float4* s4 = (const float4*)src;
    float4 A = s4[3 * i], B = s4[3 * i + 1], C = s4[3 * i + 2];

    float v[4][3] = {{A.x, A.y, A.z}, {A.w, B.x, B.y},
                     {B.z, B.w, C.x}, {C.y, C.z, C.w}};
#pragma unroll
    for (int j = 0; j < 4; ++j) {
        unsigned short hx = __half_as_ushort(__float2half_rn(v[j][0]));
        unsigned short hy = __half_as_ushort(__float2half_rn(v[j][1]));
        unsigned short hz = __half_as_ushort(__float2half_rn(v[j][2]));
        uint2 q;
        q.x = (unsigned)hx | ((unsigned)hy << 16);
        q.y = (unsigned)hz;
        dst[4 * i + j] = q;
    }
}

__global__ __launch_bounds__(256) void warp_add_h_kernel(
    const uint2* __restrict__ vol4,  // sampled field, f16 padded [B,D,H,W,4]
    const float* shift,              // current transform  [B,D,H,W,3] (may == out)
    float* out)                      // shift + interp(vol, grid+shift)
{
    // XCD swizzle: contiguous spatial slab per XCD for L2 halo reuse.
    unsigned bid  = blockIdx.x;
    unsigned sbid = (bid & 7u) * PER_XCD + (bid >> 3);

    unsigned wt  = sbid % WT_TILES;  unsigned t0 = sbid / WT_TILES;
    unsigned ht  = t0 % HT_TILES;    unsigned t1 = t0 / HT_TILES;
    unsigned dt  = t1 % DT_TILES;    unsigned b  = t1 / DT_TILES;

    unsigned tid = threadIdx.x;
    int w = wt * 64 + (tid & 63);
    int h = ht * 2  + ((tid >> 6) & 1);
    int d = dt * 2  + (tid >> 7);

    const long nvb = (long)DD * HH * WW;
    long idx = (long)b * nvb + (((long)d * HH + h) * WW + w);

    const float* sp = shift + idx * 3;
    float sx = sp[0], sy = sp[1], sz = sp[2];

    float lx = fminf(fmaxf((float)d + sx, 0.f), (float)(DD - 1));
    float ly = fminf(fmaxf((float)h + sy, 0.f), (float)(HH - 1));
    float lz = fminf(fmaxf((float)w + sz, 0.f), (float)(WW - 1));

    float fx = floorf(lx), fy = floorf(ly), fz = floorf(lz);
    int x0 = (int)fx, y0 = (int)fy, z0 = (int)fz;
    int x1 = min(x0 + 1, DD - 1);
    int y1 = min(y0 + 1, HH - 1);

    // z pair: load voxels (z0m, z0m+1); when z0==W-1 both corners use hi.
    int  z0m = min(z0, WW - 2);
    bool zhi = (z0 == WW - 1);

    float wx0 = (float)x1 - lx;
    float wy0 = (float)y1 - ly;
    float wz0 = (float)(min(z0 + 1, WW - 1)) - lz;
    float wx1 = 1.f - wx0;
    float wy1 = 1.f - wy0;
    float wz1 = 1.f - wz0;

    const uint2* baseq = vol4 + (long)b * nvb;

    float ax = 0.f, ay = 0.f, az = 0.f;
#define ROWPAIR(X, Y, WXY) do {                                             \
        const uint2* pp = baseq + (((long)(X) * HH + (Y)) * WW + z0m);      \
        uint2 qlo = pp[0], qhi = pp[1];          /* 16B adjacent */          \
        float3 vlo = cvt_h4(qlo), vhi = cvt_h4(qhi);                        \
        float3 v0  = zhi ? vhi : vlo;                                       \
        float wt_ = (WXY);                                                  \
        ax = fmaf(wt_, fmaf(wz0, v0.x, wz1 * vhi.x), ax);                   \
        ay = fmaf(wt_, fmaf(wz0, v0.y, wz1 * vhi.y), ay);                   \
        az = fmaf(wt_, fmaf(wz0, v0.z, wz1 * vhi.z), az);                   \
    } while (0)

    ROWPAIR(x0, y0, wx0 * wy0);
    ROWPAIR(x0, y1, wx0 * wy1);
    ROWPAIR(x1, y0, wx1 * wy0);
    ROWPAIR(x1, y1, wx1 * wy1);
#undef ROWPAIR

    float* op = out + idx * 3;
    op[0] = sx + ax;
    op[1] = sy + ay;
    op[2] = sz + az;
}

extern "C" void kernel_launch(void* const* d_in, const int* in_sizes, int n_in,
                              void* d_out, int out_size, void* d_ws, size_t ws_size,
                              hipStream_t stream) {
    const float* t1 = (const float*)d_in[0];
    const float* t2 = (const float*)d_in[1];
    const float* t3 = (const float*)d_in[2];
    float* out  = (float*)d_out;
    uint2* volh = (uint2*)d_ws;   // staged f16-padded volume, 63 MB (reused)

    const long nvt = (long)BB * DD * HH * WW;     // 7,864,320 voxels
    const int  conv_blocks = (int)(nvt / 4 / 256); // exact: 7680

    // Pass A: r = t3 + interp(t2, grid + t3), r -> d_out
    conv_f16_kernel<<<conv_blocks, 256, 0, stream>>>(t2, volh);
    warp_add_h_kernel<<<NBLOCKS, 256, 0, stream>>>(volh, t3, out);
    // Pass B: out = r + interp(t1, grid + r), in-place on d_out
    conv_f16_kernel<<<conv_blocks, 256, 0, stream>>>(t1, volh);
    warp_add_h_kernel<<<NBLOCKS, 256, 0, stream>>>(volh, out, out);
}

// Round 4
// 578.542 us; speedup vs baseline: 1.3653x; 1.0350x over previous
//
#include <hip/hip_runtime.h>
#include <hip/hip_fp16.h>

// ComposeTransform: out = compose([t1,t2,t3]) with dense displacement fields.
//   r   = t3 + interp(t2, grid + t3)
//   out = r  + interp(t1, grid + r)
// R3 -> R4:
//  - conv kernel rewritten with LDS transpose: coalesced float4 loads +
//    coalesced uint2 stores (was 48B/32B lane strides, 119us for 157MB).
//  - warp kernel coarsened 2 voxels/thread (adjacent w): 8 independent
//    scattered gathers in flight per thread (2x MLP vs R3), 24B contiguous
//    shift load / store per thread.
// R3 counters: warp 180us @1.75TB/s, VALU 15% => latency/transaction bound.

#define BB 2
#define DD 128
#define HH 160
#define WW 192

// warp kernel tiling: block = 256 threads x 2 voxels = 4d x 2h x 64w tile
#define WT_TILES 3   // 192/64
#define HT_TILES 80  // 160/2
#define DT_TILES 32  // 128/4
#define NBLOCKS (WT_TILES * HT_TILES * DT_TILES * BB)  // 15360
#define PER_XCD (NBLOCKS / 8)                          // 1920

static __device__ __forceinline__ float3 cvt_h4(uint2 q) {
    float2 fa = __half22float2(*(const __half2*)&q.x);
    float  fz = __half2float(*(const __half*)&q.y);
    return make_float3(fa.x, fa.y, fz);
}

// Convert f32 [.,3] field to f16 padded [.,4] (8 B/voxel).
// Block = 256 threads, 1024 voxels: 768 coalesced float4 loads -> LDS ->
// 4x coalesced uint2 stores per thread. 7680 blocks.
__global__ __launch_bounds__(256) void conv_f16_kernel(
    const float4* __restrict__ src, uint2* __restrict__ dst)
{
    __shared__ float4 lds4[768];          // 12 KB
    const float* lds = (const float*)lds4;

    long base = (long)blockIdx.x * 1024;  // first voxel of this block
    const float4* s4 = src + (long)blockIdx.x * 768;
    int tid = threadIdx.x;

#pragma unroll
    for (int j = 0; j < 3; ++j)
        lds4[tid + 256 * j] = s4[tid + 256 * j];
    __syncthreads();

#pragma unroll
    for (int j = 0; j < 4; ++j) {
        int v = tid + 256 * j;
        float x = lds[3 * v], y = lds[3 * v + 1], z = lds[3 * v + 2];
        uint2 q;
        q.x = (unsigned)__half_as_ushort(__float2half_rn(x)) |
              ((unsigned)__half_as_ushort(__float2half_rn(y)) << 16);
        q.y = (unsigned)__half_as_ushort(__float2half_rn(z));
        dst[base + v] = q;
    }
}

static __device__ __forceinline__ void interp_one(
    const uint2* __restrict__ baseq, int d, int h, int w,
    float sx, float sy, float sz, float& ox, float& oy, float& oz)
{
    float lx = fminf(fmaxf((float)d + sx, 0.f), (float)(DD - 1));
    float ly = fminf(fmaxf((float)h + sy, 0.f), (float)(HH - 1));
    float lz = fminf(fmaxf((float)w + sz, 0.f), (float)(WW - 1));

    float fx = floorf(lx), fy = floorf(ly), fz = floorf(lz);
    int x0 = (int)fx, y0 = (int)fy, z0 = (int)fz;
    int x1 = min(x0 + 1, DD - 1);
    int y1 = min(y0 + 1, HH - 1);

    int  z0m = min(z0, WW - 2);
    bool zhi = (z0 == WW - 1);

    float wx0 = (float)x1 - lx;
    float wy0 = (float)y1 - ly;
    float wz0 = (float)(min(z0 + 1, WW - 1)) - lz;
    float wx1 = 1.f - wx0;
    float wy1 = 1.f - wy0;
    float wz1 = 1.f - wz0;

    // issue all 4 row-pair loads (independent) before use
    const uint2* p00 = baseq + (((long)x0 * HH + y0) * WW + z0m);
    const uint2* p01 = baseq + (((long)x0 * HH + y1) * WW + z0m);
    const uint2* p10 = baseq + (((long)x1 * HH + y0) * WW + z0m);
    const uint2* p11 = baseq + (((long)x1 * HH + y1) * WW + z0m);
    uint2 q00l = p00[0], q00h = p00[1];
    uint2 q01l = p01[0], q01h = p01[1];
    uint2 q10l = p10[0], q10h = p10[1];
    uint2 q11l = p11[0], q11h = p11[1];

    float ax = 0.f, ay = 0.f, az = 0.f;
#define ROWPAIR(QL, QH, WXY) do {                                           \
        float3 vlo = cvt_h4(QL), vhi = cvt_h4(QH);                          \
        float3 v0  = zhi ? vhi : vlo;                                       \
        float wt_ = (WXY);                                                  \
        ax = fmaf(wt_, fmaf(wz0, v0.x, wz1 * vhi.x), ax);                   \
        ay = fmaf(wt_, fmaf(wz0, v0.y, wz1 * vhi.y), ay);                   \
        az = fmaf(wt_, fmaf(wz0, v0.z, wz1 * vhi.z), az);                   \
    } while (0)
    ROWPAIR(q00l, q00h, wx0 * wy0);
    ROWPAIR(q01l, q01h, wx0 * wy1);
    ROWPAIR(q10l, q10h, wx1 * wy0);
    ROWPAIR(q11l, q11h, wx1 * wy1);
#undef ROWPAIR

    ox = sx + ax;
    oy = sy + ay;
    oz = sz + az;
}

__global__ __launch_bounds__(256) void warp_add_h_kernel(
    const uint2* __restrict__ vol4,  // sampled field, f16 padded [B,D,H,W,4]
    const float* shift,              // current transform (may alias out)
    float* out)
{
    // XCD swizzle: contiguous spatial slab per XCD for L2 halo reuse.
    unsigned bid  = blockIdx.x;
    unsigned sbid = (bid & 7u) * PER_XCD + (bid >> 3);

    unsigned wt  = sbid % WT_TILES;  unsigned t0 = sbid / WT_TILES;
    unsigned ht  = t0 % HT_TILES;    unsigned t1 = t0 / HT_TILES;
    unsigned dt  = t1 % DT_TILES;    unsigned b  = t1 / DT_TILES;

    unsigned tid = threadIdx.x;
    int w = wt * 64 + 2 * (tid & 31);        // even; handles w, w+1
    int h = ht * 2  + ((tid >> 5) & 1);
    int d = dt * 4  + (tid >> 6);

    const long nvb = (long)DD * HH * WW;
    long idx = (long)b * nvb + (((long)d * HH + h) * WW + w);

    // 2 voxels' shifts: 6 contiguous floats, 8B-aligned
    const float2* sp2 = (const float2*)(shift + idx * 3);
    float2 sa = sp2[0], sb = sp2[1], sc = sp2[2];

    const uint2* baseq = vol4 + (long)b * nvb;

    float o0x, o0y, o0z, o1x, o1y, o1z;
    interp_one(baseq, d, h, w,     sa.x, sa.y, sb.x, o0x, o0y, o0z);
    interp_one(baseq, d, h, w + 1, sb.y, sc.x, sc.y, o1x, o1y, o1z);

    float2* op2 = (float2*)(out + idx * 3);
    op2[0] = make_float2(o0x, o0y);
    op2[1] = make_float2(o0z, o1x);
    op2[2] = make_float2(o1y, o1z);
}

extern "C" void kernel_launch(void* const* d_in, const int* in_sizes, int n_in,
                              void* d_out, int out_size, void* d_ws, size_t ws_size,
                              hipStream_t stream) {
    const float* t1 = (const float*)d_in[0];
    const float* t2 = (const float*)d_in[1];
    const float* t3 = (const float*)d_in[2];
    float* out  = (float*)d_out;
    uint2* volh = (uint2*)d_ws;   // staged f16-padded volume, 63 MB (reused)

    const long nvt = (long)BB * DD * HH * WW;      // 7,864,320 voxels
    const int  conv_blocks = (int)(nvt / 1024);    // exact: 7680

    // Pass A: r = t3 + interp(t2, grid + t3), r -> d_out
    conv_f16_kernel<<<conv_blocks, 256, 0, stream>>>((const float4*)t2, volh);
    warp_add_h_kernel<<<NBLOCKS, 256, 0, stream>>>(volh, t3, out);
    // Pass B: out = r + interp(t1, grid + r), in-place on d_out
    conv_f16_kernel<<<conv_blocks, 256, 0, stream>>>((const float4*)t1, volh);
    warp_add_h_kernel<<<NBLOCKS, 256, 0, stream>>>(volh, out, out);
}